// Round 19
// baseline (140.597 us; speedup 1.0000x reference)
//
#include <hip/hip_runtime.h>

namespace {
constexpr int N = 100000;
constexpr int E = 1600000;
constexpr int D = 128;
constexpr int U = 64;
constexpr int C = 40;
constexpr int C2 = C / 2;   // 20 packed bf16x2 words per row
constexpr int RP = 32;      // padded gather-row stride in u32 (128 B)
constexpr int SLOTS = 64;   // padded CSR slots per node
constexpr int NBK = (N + 63) / 64;   // 1563 buckets of 64 nodes (bucket = dst >> 6)
constexpr int CAP = 1280;   // bucket capacity: Poisson(1024) + 8 sigma
constexpr int EPB = 16;
constexpr int TPB = 256;
constexpr int GK = 136;     // padded Gbf/A row stride in bf16 (272 B)
constexpr int PROJ_BLOCKS = (N + 63) / 64;  // 1563

// workspace layout (element offsets; 4-byte units; all regions 128B-aligned)
constexpr size_t OFF_BCUR = 0;                               // 2048 ints
constexpr size_t OFF_META = OFF_BCUR + 2048;                 // 2*N ints: {cnt, rdeg_bits}
constexpr size_t OFF_CSR = OFF_META + (size_t)2 * N;         // 2*N*SLOTS ints
constexpr size_t OFF_BBUF = OFF_CSR + (size_t)2 * N * SLOTS; // NBK*CAP*2 ints
constexpr size_t BBUF_INTS = (size_t)NBK * CAP * 2;
constexpr size_t OFF_P1 = OFF_BBUF + BBUF_INTS;              // N*C floats (fp32)
constexpr size_t OFF_P2B = OFF_P1 + (size_t)N * C + 32;      // N*RP u32
constexpr size_t OFF_RBF = OFF_P2B + (size_t)N * RP;         // N*RP u32
constexpr size_t OFF_GBF = OFF_RBF + (size_t)N * RP;         // 128*GK u16 = 8704 u32
constexpr size_t OFF_BC = OFF_GBF + 128 * GK / 2;            // C floats

constexpr int SMEM_FUSED = 64 * GK * 2 + 256;  // a_s (17.4 KB) + bc_s -> ~17.7 KB
} // namespace

// ---- bf16 pack/unpack (RNE) ----
__device__ inline unsigned f2bf(float x) {
    unsigned u = __float_as_uint(x);
    return (u + 0x7fffu + ((u >> 16) & 1u)) >> 16;
}
__device__ inline unsigned pack_bf2(float a, float b) { return f2bf(a) | (f2bf(b) << 16); }
__device__ inline float2 unpack_bf2(unsigned v) {
    return make_float2(__uint_as_float(v << 16), __uint_as_float(v & 0xffff0000u));
}

typedef __attribute__((ext_vector_type(8))) short bf16x8;
typedef __attribute__((ext_vector_type(4))) float f32x4;

// ---- fold weights into one bf16 B^T matrix Gbf[n][k] (n: 0-39 G0, 40-79 G1, 80-119 G2)
// plus bc = b@Wd + bd. Block 0 zeroes the bucket cursors.
__global__ void prep_weights(const float* __restrict__ W, const float* __restrict__ b,
                             const float* __restrict__ Wd, const float* __restrict__ bd,
                             unsigned short* __restrict__ Gbf, float* __restrict__ bc,
                             int* __restrict__ bcur) {
    if (blockIdx.x == 0) {
        for (int i = threadIdx.x; i < 2048; i += 256) bcur[i] = 0;
    }
    int t = blockIdx.x * blockDim.x + threadIdx.x;
    if (t < 128 * 128) {
        int n = t >> 7, k = t & 127;
        float s = 0.f;
        if (n < 40) {
            const float* W0 = W + (size_t)k * U;
            const float* W2 = W + (size_t)2 * D * U + (size_t)k * U;
            for (int u = 0; u < U; ++u) s += (W0[u] - W2[u]) * Wd[u * C + n];
        } else if (n < 80) {
            const float* W1 = W + (size_t)D * U + (size_t)k * U;
            for (int u = 0; u < U; ++u) s -= W1[u] * Wd[u * C + (n - 40)];
        } else if (n < 120) {
            const float* W2 = W + (size_t)2 * D * U + (size_t)k * U;
            for (int u = 0; u < U; ++u) s += 2.f * W2[u] * Wd[u * C + (n - 80)];
        }
        Gbf[n * GK + k] = (unsigned short)f2bf(s);
    } else if (t < 128 * 128 + C) {
        int c = t - 128 * 128;
        float s = bd[c];
        for (int u = 0; u < U; ++u) s += b[u] * Wd[u * C + c];
        bc[c] = s;
    }
}

// Pass C: two-level counting scatter into per-bucket regions (64-node buckets).
// Records int2: w0 = src | (dst & 63) << 24 ; w1 = ew bits.
__global__ __launch_bounds__(TPB) void bucket_scatter(const int* __restrict__ src,
                                                      const int* __restrict__ dst,
                                                      const float* __restrict__ ew,
                                                      int* __restrict__ bcur,
                                                      int2* __restrict__ bbuf2) {
    __shared__ int hist[NBK];
    __shared__ int base[NBK];
    int t = threadIdx.x;
    for (int i = t; i < NBK; i += TPB) hist[i] = 0;
    __syncthreads();

    size_t e0 = (size_t)blockIdx.x * (TPB * EPB);
    int ms[EPB], md[EPB], mw[EPB], mr[EPB];
#pragma unroll
    for (int k = 0; k < EPB; ++k) {
        size_t e = e0 + (size_t)k * TPB + t;
        if (e < E) {
            ms[k] = src[e];
            md[k] = dst[e];
            mw[k] = __float_as_int(ew[e]);
            mr[k] = atomicAdd(&hist[md[k] >> 6], 1);
        } else {
            md[k] = -1;
        }
    }
    __syncthreads();
    for (int i = t; i < NBK; i += TPB) {
        int c = hist[i];
        base[i] = c ? atomicAdd(&bcur[i], c) : 0;
    }
    __syncthreads();
#pragma unroll
    for (int k = 0; k < EPB; ++k) {
        if (md[k] >= 0) {
            int bkt = md[k] >> 6;
            int slot = base[bkt] + mr[k];
            if (slot < CAP)
                bbuf2[(size_t)bkt * CAP + slot] =
                    make_int2(ms[k] | ((md[k] & 63) << 24), mw[k]);
        }
    }
}

// Fused kernel: blocks [0,NBK) csr_build on 64-node buckets (1563 blocks ->
// ~6 waves/SIMD, 4x the latency hiding of the 256-node version); blocks
// [NBK, NBK+PROJ_BLOCKS) MFMA projection (A in LDS, G direct from global).
__global__ __launch_bounds__(256) void csr_and_proj(
    const int* __restrict__ bcur, const int2* __restrict__ bbuf2,
    int2* __restrict__ meta, int2* __restrict__ csr,
    const float* __restrict__ X, const unsigned short* __restrict__ Gbf,
    const float* __restrict__ bc, float* __restrict__ out,
    float* __restrict__ P1, unsigned short* __restrict__ P2B16) {
    __shared__ __align__(16) unsigned char smem[SMEM_FUSED];
    int t = threadIdx.x;

    if (blockIdx.x < NBK) {
        // ---- csr_build: one pass over ~1024 records (4 iterations of 256).
        int* lcur = (int*)smem;              // 64 counters
        float* lw = (float*)(smem + 256);    // 64 weight sums
        int b = blockIdx.x;
        if (t < 64) {
            lcur[t] = 0;
            lw[t] = 0.f;
        }
        __syncthreads();
        int cnt = min(bcur[b], CAP);
        const int2* bb = bbuf2 + (size_t)b * CAP;
        for (int i = t; i < cnt; i += 256) {
            int2 r = bb[i];
            int idx = ((unsigned)r.x) >> 24;     // 0..63
            int slot = atomicAdd(&lcur[idx], 1);
            atomicAdd(&lw[idx], __int_as_float(r.y));
            if (slot < SLOTS)
                csr[(((size_t)(b << 6) + idx) << 6) + slot] =
                    make_int2(r.x & 0x00FFFFFF, r.y);
        }
        __syncthreads();
        if (t < 64) {
            int node = (b << 6) + t;
            if (node < N) {
                int c = min(lcur[t], SLOTS);
                float rdeg = 1.f / fmaxf(lw[t], 1e-12f);
                meta[node] = make_int2(c, __float_as_int(rdeg));
                int padded = min((c + 15) & ~15, SLOTS);
                for (int s = c; s < padded; ++s)
                    csr[((size_t)node << 6) + s] = make_int2(0, 0);
            }
        }
        return;
    }

    // ---- proj: [64x128] @ [128x120] bf16 MFMA GEMM per 64-row tile.
    //   cols 0-39 -> out(+bc, fp32) ; 40-79 -> P1 (fp32) ; 80-119 -> P2B (bf16 u16)
    int rb = blockIdx.x - NBK;
    unsigned short* a_s = (unsigned short*)smem;              // 64*GK u16
    float* bc_s = (float*)(smem + 64 * GK * 2);               // C floats
    if (t < C) bc_s[t] = bc[t];

    // stage A: 64 rows x 32 float4 (coalesced), convert to bf16
#pragma unroll
    for (int i = 0; i < 8; ++i) {
        int idx = i * 256 + t;
        int row = idx >> 5, kq = idx & 31;
        size_t grow = (size_t)rb * 64 + row;
        float4 v = (grow < N) ? ((const float4*)X)[grow * 32 + kq]
                              : make_float4(0.f, 0.f, 0.f, 0.f);
        unsigned* dstp = (unsigned*)(a_s + row * GK + kq * 4);
        dstp[0] = pack_bf2(v.x, v.y);
        dstp[1] = pack_bf2(v.z, v.w);
    }
    __syncthreads();

    int w = t >> 6, l = t & 63;
    int lr = l & 15, lh = l >> 4;

    bf16x8 afr[4];
#pragma unroll
    for (int ks = 0; ks < 4; ++ks)
        afr[ks] = *(const bf16x8*)(a_s + (w * 16 + lr) * GK + ks * 32 + lh * 8);

    f32x4 acc[8];
#pragma unroll
    for (int tt = 0; tt < 8; ++tt) {
        acc[tt] = (f32x4){0.f, 0.f, 0.f, 0.f};
#pragma unroll
        for (int ks = 0; ks < 4; ++ks) {
            // B-fragment direct from global (L1/L2-hit 16B lane loads)
            bf16x8 bfr = *(const bf16x8*)(Gbf + (tt * 16 + lr) * GK + ks * 32 + lh * 8);
            acc[tt] = __builtin_amdgcn_mfma_f32_16x16x32_bf16(afr[ks], bfr, acc[tt], 0, 0, 0);
        }
    }

    // epilogue: C/D mapping col = tt*16 + (lane&15), row = (lane>>4)*4 + reg
#pragma unroll
    for (int tt = 0; tt < 8; ++tt) {
        int gcol = tt * 16 + lr;
#pragma unroll
        for (int r = 0; r < 4; ++r) {
            size_t grow = (size_t)rb * 64 + w * 16 + lh * 4 + r;
            if (grow >= N) continue;
            float v = acc[tt][r];
            if (gcol < 40) {
                out[grow * C + gcol] = v + bc_s[gcol];
            } else if (gcol < 80) {
                P1[grow * C + (gcol - 40)] = v;
            } else if (gcol < 120) {
                P2B16[grow * 64 + (gcol - 80)] = (unsigned short)f2bf(v);
            }
        }
    }
}

// gather SpMM (r17 v4, unchanged): scalar metadata + precomputed rdeg + 16-edge
// batches.  Y[n] = Add[n] + rdeg * sum_e w_e * Xg[src_e]
// OUT_BF=true: Add = P1 (fp32), Y = Rbf (bf16, full 128B padded rows).
// OUT_BF=false: Add = out (fp32), Y = out (fp32).
template <bool OUT_BF>
__global__ __launch_bounds__(256) void spmm40v4(const int2* __restrict__ meta,
                                                const int2* __restrict__ csr,
                                                const unsigned* __restrict__ Xg,
                                                const float* __restrict__ Add,
                                                void* __restrict__ Yv) {
    int wid = (blockIdx.x * blockDim.x + threadIdx.x) >> 6;
    if (wid >= N) return;
    int uw = __builtin_amdgcn_readfirstlane(wid);
    int2 m = meta[uw];                     // uniform -> s_load_dwordx2
    int c = m.x;
    float rdeg = __int_as_float(m.y);
    const int2* __restrict__ row = csr + ((size_t)uw << 6);
    int lane = threadIdx.x & 63;
    bool hi = lane >= 32;
    unsigned voff = (unsigned)(lane & 31); // word index within padded 32-word row

    float2 ad = make_float2(0.f, 0.f);
    if (lane < C2) ad = ((const float2*)Add)[(size_t)wid * C2 + lane];

    float2 acc = make_float2(0.f, 0.f);
    for (int j0 = 0; j0 < c; j0 += 16) {
        unsigned va[8];
        float wa[8];
#pragma unroll
        for (int k = 0; k < 8; ++k) {
            int2 a = row[j0 + k];          // uniform -> s_load
            int2 b = row[j0 + 8 + k];
            int col = hi ? b.x : a.x;
            wa[k] = __int_as_float(hi ? b.y : a.y);
            va[k] = Xg[((unsigned)col << 5) + voff];  // SGPR base + 32-bit voffset
        }
#pragma unroll
        for (int k = 0; k < 8; ++k) {
            float2 v = unpack_bf2(va[k]);
            acc.x = fmaf(wa[k], v.x, acc.x);
            acc.y = fmaf(wa[k], v.y, acc.y);
        }
    }
    acc.x += __shfl_xor(acc.x, 32);
    acc.y += __shfl_xor(acc.y, 32);

    if (OUT_BF) {
        if (lane < 32) {
            unsigned o = 0u;
            if (lane < C2)
                o = pack_bf2(fmaf(acc.x, rdeg, ad.x), fmaf(acc.y, rdeg, ad.y));
            ((unsigned*)Yv)[((size_t)wid << 5) + lane] = o;  // full 128B row, no RMW
        }
    } else {
        if (lane < C2) {
            ((float2*)Yv)[(size_t)wid * C2 + lane] =
                make_float2(fmaf(acc.x, rdeg, ad.x), fmaf(acc.y, rdeg, ad.y));
        }
    }
}

extern "C" void kernel_launch(void* const* d_in, const int* in_sizes, int n_in,
                              void* d_out, int out_size, void* d_ws, size_t ws_size,
                              hipStream_t stream) {
    const float* x = (const float*)d_in[0];
    const int* ei = (const int*)d_in[1];   // (2, E): src = ei, dst = ei + E
    const float* ew = (const float*)d_in[2];
    const float* W = (const float*)d_in[3];
    const float* b = (const float*)d_in[4];
    const float* Wd = (const float*)d_in[5];
    const float* bd = (const float*)d_in[6];
    float* out = (float*)d_out;

    const int* src = ei;
    const int* dst = ei + E;

    float* ws = (float*)d_ws;
    int* bcur = (int*)(ws + OFF_BCUR);
    int2* meta = (int2*)(ws + OFF_META);
    int2* csr = (int2*)(ws + OFF_CSR);
    int2* bbuf2 = (int2*)(ws + OFF_BBUF);
    float* P1 = ws + OFF_P1;
    unsigned* P2B = (unsigned*)(ws + OFF_P2B);
    unsigned* Rbf = (unsigned*)(ws + OFF_RBF);
    unsigned short* Gbf = (unsigned short*)(ws + OFF_GBF);
    float* bc = ws + OFF_BC;

    // prep: fold weights + zero bucket cursors (no memset dispatch)
    prep_weights<<<(128 * 128 + C + 255) / 256, 256, 0, stream>>>(W, b, Wd, bd, Gbf, bc, bcur);

    // two-level counting sort, 64-node buckets, packed int2 records
    bucket_scatter<<<(E + TPB * EPB - 1) / (TPB * EPB), TPB, 0, stream>>>(src, dst, ew, bcur, bbuf2);

    // fused: csr_build (1563 blocks, 64-node buckets) || proj (1563 blocks)
    csr_and_proj<<<NBK + PROJ_BLOCKS, 256, 0, stream>>>(bcur, bbuf2, meta, csr, x, Gbf, bc,
                                                        out, P1, (unsigned short*)P2B);

    // Rbf = bf16(P1 + A_hat @ P2)
    spmm40v4<true><<<((size_t)N * 64 + 255) / 256, 256, 0, stream>>>(meta, csr, P2B, P1, Rbf);
    // out += A_hat @ R
    spmm40v4<false><<<((size_t)N * 64 + 255) / 256, 256, 0, stream>>>(meta, csr, Rbf, out, out);
}

// Round 20
// 131.474 us; speedup vs baseline: 1.0694x; 1.0694x over previous
//
#include <hip/hip_runtime.h>

namespace {
constexpr int N = 100000;
constexpr int E = 1600000;
constexpr int D = 128;
constexpr int U = 64;
constexpr int C = 40;
constexpr int C2 = C / 2;   // 20 packed bf16x2 words per row
constexpr int RP = 32;      // padded row stride in u32 (128 B)
constexpr int SLOTS = 64;   // padded CSR slots per node; deg ~ Poisson(16), P(>64) ~ 1e-15
constexpr int NB = (N + 255) / 256;  // 391 buckets of 256 nodes
constexpr int CAP = 4608;   // bucket capacity
constexpr int EPB = 16;
constexpr int TPB = 256;
constexpr int GK = 136;     // padded Gbf/A row stride in bf16 (272 B: 2-way alias = free)
constexpr int PROJ_BLOCKS = (N + 63) / 64;  // 1563

// workspace layout (element offsets; 4-byte units)
constexpr size_t OFF_BCUR = 0;                               // 512 ints
constexpr size_t OFF_META = OFF_BCUR + 512;                  // 2*N ints: {cnt, rdeg_bits}
constexpr size_t OFF_CSR = OFF_META + (size_t)2 * N;         // 2*N*SLOTS ints
constexpr size_t OFF_BBUF = OFF_CSR + (size_t)2 * N * SLOTS; // NB*CAP*2 ints (packed int2)
constexpr size_t BBUF_INTS = (size_t)NB * CAP * 2;
constexpr size_t OFF_P1 = OFF_BBUF + BBUF_INTS;              // N*C floats
constexpr size_t OFF_P2B = OFF_P1 + (size_t)N * C + 32;      // N*RP u32
constexpr size_t OFF_RBF = OFF_P2B + (size_t)N * RP;         // N*RP u32
constexpr size_t OFF_GBF = OFF_RBF + (size_t)N * RP;         // 128*GK u16 = 8704 u32
constexpr size_t OFF_BC = OFF_GBF + 128 * GK / 2;            // C floats

constexpr int SMEM_PROJ = 64 * GK * 2 + 128 * GK * 2 + ((C * 4 + 15) & ~15);  // 52.4 KB
} // namespace

// ---- bf16 pack/unpack (RNE) ----
__device__ inline unsigned f2bf(float x) {
    unsigned u = __float_as_uint(x);
    return (u + 0x7fffu + ((u >> 16) & 1u)) >> 16;
}
__device__ inline unsigned pack_bf2(float a, float b) { return f2bf(a) | (f2bf(b) << 16); }
__device__ inline float2 unpack_bf2(unsigned v) {
    return make_float2(__uint_as_float(v << 16), __uint_as_float(v & 0xffff0000u));
}

typedef __attribute__((ext_vector_type(8))) short bf16x8;
typedef __attribute__((ext_vector_type(4))) float f32x4;

// ---- fold weights into one bf16 B^T matrix Gbf[n][k] (n: 0-39 G0, 40-79 G1, 80-119 G2)
// plus bc = b@Wd + bd. Block 0 zeroes the bucket cursors (no memset dispatch).
__global__ void prep_weights(const float* __restrict__ W, const float* __restrict__ b,
                             const float* __restrict__ Wd, const float* __restrict__ bd,
                             unsigned short* __restrict__ Gbf, float* __restrict__ bc,
                             int* __restrict__ bcur) {
    if (blockIdx.x == 0) {
        for (int i = threadIdx.x; i < 512; i += 256) bcur[i] = 0;
    }
    int t = blockIdx.x * blockDim.x + threadIdx.x;
    if (t < 128 * 128) {
        int n = t >> 7, k = t & 127;
        float s = 0.f;
        if (n < 40) {
            const float* W0 = W + (size_t)k * U;
            const float* W2 = W + (size_t)2 * D * U + (size_t)k * U;
            for (int u = 0; u < U; ++u) s += (W0[u] - W2[u]) * Wd[u * C + n];
        } else if (n < 80) {
            const float* W1 = W + (size_t)D * U + (size_t)k * U;
            for (int u = 0; u < U; ++u) s -= W1[u] * Wd[u * C + (n - 40)];
        } else if (n < 120) {
            const float* W2 = W + (size_t)2 * D * U + (size_t)k * U;
            for (int u = 0; u < U; ++u) s += 2.f * W2[u] * Wd[u * C + (n - 80)];
        }
        Gbf[n * GK + k] = (unsigned short)f2bf(s);
    } else if (t < 128 * 128 + C) {
        int c = t - 128 * 128;
        float s = bd[c];
        for (int u = 0; u < U; ++u) s += b[u] * Wd[u * C + c];
        bc[c] = s;
    }
}

// Pass C: two-level counting scatter. Records int2: w0 = src | dst_low8<<24 ; w1 = ew.
__global__ __launch_bounds__(TPB) void bucket_scatter(const int* __restrict__ src,
                                                      const int* __restrict__ dst,
                                                      const float* __restrict__ ew,
                                                      int* __restrict__ bcur,
                                                      int2* __restrict__ bbuf2) {
    __shared__ int hist[NB];
    __shared__ int base[NB];
    int t = threadIdx.x;
    for (int i = t; i < NB; i += TPB) hist[i] = 0;
    __syncthreads();

    size_t e0 = (size_t)blockIdx.x * (TPB * EPB);
    int ms[EPB], md[EPB], mw[EPB], mr[EPB];
#pragma unroll
    for (int k = 0; k < EPB; ++k) {
        size_t e = e0 + (size_t)k * TPB + t;
        if (e < E) {
            ms[k] = src[e];
            md[k] = dst[e];
            mw[k] = __float_as_int(ew[e]);
            mr[k] = atomicAdd(&hist[md[k] >> 8], 1);
        } else {
            md[k] = -1;
        }
    }
    __syncthreads();
    for (int i = t; i < NB; i += TPB) {
        int c = hist[i];
        base[i] = c ? atomicAdd(&bcur[i], c) : 0;
    }
    __syncthreads();
#pragma unroll
    for (int k = 0; k < EPB; ++k) {
        if (md[k] >= 0) {
            int bkt = md[k] >> 8;
            int slot = base[bkt] + mr[k];
            if (slot < CAP)
                bbuf2[(size_t)bkt * CAP + slot] =
                    make_int2(ms[k] | ((md[k] & 255) << 24), mw[k]);
        }
    }
}

// Fused kernel: blocks [0, NB) run csr_build; blocks [NB, NB+PROJ_BLOCKS) run
// proj_mfma. Independent phases overlap on the grid (r12-measured best).
__global__ __launch_bounds__(256) void csr_and_proj(
    const int* __restrict__ bcur, const int2* __restrict__ bbuf2,
    int2* __restrict__ meta, int2* __restrict__ csr,
    const float* __restrict__ X, const unsigned* __restrict__ Gu,
    const float* __restrict__ bc, float* __restrict__ out,
    float* __restrict__ P1, unsigned short* __restrict__ P2B16) {
    __shared__ __align__(16) unsigned char smem[SMEM_PROJ];
    int t = threadIdx.x;

    if (blockIdx.x < NB) {
        // ---- csr_build: one pass, LDS-only slotting + weighted degree; pad to 16.
        int* lcur = (int*)smem;
        float* lw = (float*)(smem + 1024);
        int b = blockIdx.x;
        lcur[t] = 0;
        lw[t] = 0.f;
        __syncthreads();
        int cnt = min(bcur[b], CAP);
        const int2* bb = bbuf2 + (size_t)b * CAP;
        for (int i = t; i < cnt; i += 256) {
            int2 r = bb[i];
            int idx = ((unsigned)r.x) >> 24;
            int slot = atomicAdd(&lcur[idx], 1);
            atomicAdd(&lw[idx], __int_as_float(r.y));
            if (slot < SLOTS)
                csr[(((size_t)(b << 8) + idx) << 6) + slot] =
                    make_int2(r.x & 0x00FFFFFF, r.y);
        }
        __syncthreads();
        int node = (b << 8) + t;
        if (node < N) {
            int c = min(lcur[t], SLOTS);
            float rdeg = 1.f / fmaxf(lw[t], 1e-12f);
            meta[node] = make_int2(c, __float_as_int(rdeg));
            int padded = min((c + 15) & ~15, SLOTS);
            for (int s = c; s < padded; ++s)
                csr[((size_t)node << 6) + s] = make_int2(0, 0);
        }
        return;
    }

    // ---- proj_mfma: [64x128] @ [128x120] bf16 MFMA GEMM per 64-row tile
    //   cols 0-39 -> out(+bc, fp32) ; 40-79 -> P1 (fp32) ; 80-119 -> P2B (bf16 u16)
    int rb = blockIdx.x - NB;
    unsigned short* a_s = (unsigned short*)smem;                     // 64*GK
    unsigned short* g_s = (unsigned short*)(smem + 64 * GK * 2);     // 128*GK
    float* bc_s = (float*)(smem + 64 * GK * 2 + 128 * GK * 2);       // C

    unsigned* gsu = (unsigned*)g_s;
    for (int i = t; i < 128 * GK / 2; i += 256) gsu[i] = Gu[i];
    if (t < C) bc_s[t] = bc[t];

#pragma unroll
    for (int i = 0; i < 8; ++i) {
        int idx = i * 256 + t;
        int row = idx >> 5, kq = idx & 31;
        size_t grow = (size_t)rb * 64 + row;
        float4 v = (grow < N) ? ((const float4*)X)[grow * 32 + kq]
                              : make_float4(0.f, 0.f, 0.f, 0.f);
        unsigned* dstp = (unsigned*)(a_s + row * GK + kq * 4);
        dstp[0] = pack_bf2(v.x, v.y);
        dstp[1] = pack_bf2(v.z, v.w);
    }
    __syncthreads();

    int w = t >> 6, l = t & 63;
    int lr = l & 15, lh = l >> 4;

    bf16x8 afr[4];
#pragma unroll
    for (int ks = 0; ks < 4; ++ks)
        afr[ks] = *(const bf16x8*)(a_s + (w * 16 + lr) * GK + ks * 32 + lh * 8);

    f32x4 acc[8];
#pragma unroll
    for (int tt = 0; tt < 8; ++tt) {
        acc[tt] = (f32x4){0.f, 0.f, 0.f, 0.f};
#pragma unroll
        for (int ks = 0; ks < 4; ++ks) {
            bf16x8 bfr = *(const bf16x8*)(g_s + (tt * 16 + lr) * GK + ks * 32 + lh * 8);
            acc[tt] = __builtin_amdgcn_mfma_f32_16x16x32_bf16(afr[ks], bfr, acc[tt], 0, 0, 0);
        }
    }

    // epilogue: C/D mapping col = tt*16 + (lane&15), row = (lane>>4)*4 + reg
#pragma unroll
    for (int tt = 0; tt < 8; ++tt) {
        int gcol = tt * 16 + lr;
#pragma unroll
        for (int r = 0; r < 4; ++r) {
            size_t grow = (size_t)rb * 64 + w * 16 + lh * 4 + r;
            if (grow >= N) continue;
            float v = acc[tt][r];
            if (gcol < 40) {
                out[grow * C + gcol] = v + bc_s[gcol];
            } else if (gcol < 80) {
                P1[grow * C + (gcol - 40)] = v;
            } else if (gcol < 120) {
                P2B16[grow * 64 + (gcol - 80)] = (unsigned short)f2bf(v);
            }
        }
    }
}

// gather SpMM v4: scalar metadata + precomputed rdeg + 16-edge batches.
//   Y[n] = Add[n] + rdeg * sum_e w_e * Xg[src_e]
// OUT_BF=true: Add = P1 (fp32), Y = Rbf (bf16, full 128B padded rows).
// OUT_BF=false: Add = out (fp32), Y = out (fp32).
template <bool OUT_BF>
__global__ __launch_bounds__(256) void spmm40v4(const int2* __restrict__ meta,
                                                const int2* __restrict__ csr,
                                                const unsigned* __restrict__ Xg,
                                                const float* __restrict__ Add,
                                                void* __restrict__ Yv) {
    int wid = (blockIdx.x * blockDim.x + threadIdx.x) >> 6;
    if (wid >= N) return;
    int uw = __builtin_amdgcn_readfirstlane(wid);
    int2 m = meta[uw];                     // uniform -> s_load_dwordx2
    int c = m.x;
    float rdeg = __int_as_float(m.y);
    const int2* __restrict__ row = csr + ((size_t)uw << 6);
    int lane = threadIdx.x & 63;
    bool hi = lane >= 32;
    unsigned voff = (unsigned)(lane & 31); // word index within padded 32-word row

    float2 ad = make_float2(0.f, 0.f);
    if (lane < C2) ad = ((const float2*)Add)[(size_t)wid * C2 + lane];

    float2 acc = make_float2(0.f, 0.f);
    for (int j0 = 0; j0 < c; j0 += 16) {
        unsigned va[8];
        float wa[8];
#pragma unroll
        for (int k = 0; k < 8; ++k) {
            int2 a = row[j0 + k];          // uniform -> s_load
            int2 b = row[j0 + 8 + k];
            int col = hi ? b.x : a.x;
            wa[k] = __int_as_float(hi ? b.y : a.y);
            va[k] = Xg[((unsigned)col << 5) + voff];  // SGPR base + 32-bit voffset
        }
#pragma unroll
        for (int k = 0; k < 8; ++k) {
            float2 v = unpack_bf2(va[k]);
            acc.x = fmaf(wa[k], v.x, acc.x);
            acc.y = fmaf(wa[k], v.y, acc.y);
        }
    }
    acc.x += __shfl_xor(acc.x, 32);
    acc.y += __shfl_xor(acc.y, 32);

    if (OUT_BF) {
        if (lane < 32) {
            unsigned o = 0u;
            if (lane < C2)
                o = pack_bf2(fmaf(acc.x, rdeg, ad.x), fmaf(acc.y, rdeg, ad.y));
            ((unsigned*)Yv)[((size_t)wid << 5) + lane] = o;  // full 128B row, no RMW
        }
    } else {
        if (lane < C2) {
            ((float2*)Yv)[(size_t)wid * C2 + lane] =
                make_float2(fmaf(acc.x, rdeg, ad.x), fmaf(acc.y, rdeg, ad.y));
        }
    }
}

extern "C" void kernel_launch(void* const* d_in, const int* in_sizes, int n_in,
                              void* d_out, int out_size, void* d_ws, size_t ws_size,
                              hipStream_t stream) {
    const float* x = (const float*)d_in[0];
    const int* ei = (const int*)d_in[1];   // (2, E): src = ei, dst = ei + E
    const float* ew = (const float*)d_in[2];
    const float* W = (const float*)d_in[3];
    const float* b = (const float*)d_in[4];
    const float* Wd = (const float*)d_in[5];
    const float* bd = (const float*)d_in[6];
    float* out = (float*)d_out;

    const int* src = ei;
    const int* dst = ei + E;

    float* ws = (float*)d_ws;
    int* bcur = (int*)(ws + OFF_BCUR);
    int2* meta = (int2*)(ws + OFF_META);
    int2* csr = (int2*)(ws + OFF_CSR);
    int2* bbuf2 = (int2*)(ws + OFF_BBUF);
    float* P1 = ws + OFF_P1;
    unsigned* P2B = (unsigned*)(ws + OFF_P2B);
    unsigned* Rbf = (unsigned*)(ws + OFF_RBF);
    unsigned short* Gbf = (unsigned short*)(ws + OFF_GBF);
    float* bc = ws + OFF_BC;

    // prep: fold weights + zero bucket cursors (no memset dispatch)
    prep_weights<<<(128 * 128 + C + 255) / 256, 256, 0, stream>>>(W, b, Wd, bd, Gbf, bc, bcur);

    // two-level counting sort, packed int2 records
    bucket_scatter<<<(E + TPB * EPB - 1) / (TPB * EPB), TPB, 0, stream>>>(src, dst, ew, bcur, bbuf2);

    // fused: csr_build (391 blocks) || proj_mfma (1563 blocks)
    csr_and_proj<<<NB + PROJ_BLOCKS, 256, 0, stream>>>(bcur, bbuf2, meta, csr, x,
                                                       (const unsigned*)Gbf, bc, out, P1,
                                                       (unsigned short*)P2B);

    // Rbf = bf16(P1 + A_hat @ P2)
    spmm40v4<true><<<((size_t)N * 64 + 255) / 256, 256, 0, stream>>>(meta, csr, P2B, P1, Rbf);
    // out += A_hat @ R
    spmm40v4<false><<<((size_t)N * 64 + 255) / 256, 256, 0, stream>>>(meta, csr, Rbf, out, out);
}